// Round 1
// baseline (12030.437 us; speedup 1.0000x reference)
//
#include <hip/hip_runtime.h>

#define NB 128      // batch
#define NT 512      // time steps
#define DIN 256     // layer-0 input dim
#define DD 512      // hidden dim

using bf16x8 = __attribute__((ext_vector_type(8))) short;
using f32x4v = __attribute__((ext_vector_type(4))) float;
using u32x4  = __attribute__((ext_vector_type(4))) unsigned int;

__device__ __forceinline__ unsigned short f2bf(float f) {
  unsigned int u = __builtin_bit_cast(unsigned int, f);
  u = (u + 0x7fffu + ((u >> 16) & 1u)) >> 16;
  return (unsigned short)u;
}
__device__ __forceinline__ float bf2f(unsigned short h) {
  unsigned int u = ((unsigned int)h) << 16;
  return __builtin_bit_cast(float, u);
}
// pack fp32 -> (bf16 hi | bf16 lo) in one dword: split-bf16 keeps the 512-step recurrence accurate
__device__ __forceinline__ unsigned int packf(float v) {
  unsigned short hi = f2bf(v);
  unsigned short lo = f2bf(v - bf2f(hi));
  return (((unsigned int)hi) << 16) | lo;
}

// ---------------- prep: pack x, zero state parities & group counters ----------------
__global__ void prep_kernel(const float* __restrict__ x, unsigned int* __restrict__ x_pk,
                            unsigned int* __restrict__ hp, unsigned int* __restrict__ cnt) {
  long i = (long)blockIdx.x * blockDim.x + threadIdx.x;
  const long stride = (long)gridDim.x * blockDim.x;
  const long NX = (long)NB * NT * DIN;
  for (long j = i; j < NX; j += stride) x_pk[j] = packf(x[j]);
  const long NH = 2L * 2 * NB * DD;              // [parity][layer][row][col]
  for (long j = i; j < NH; j += stride) hp[j] = 0u;
  if (i < 256) cnt[i] = 0u;                      // re-zero every launch (ws poisoned 0xAA)
}

__device__ __forceinline__ void unpack16(const u32x4& q0, const u32x4& q1,
                                         bf16x8& hi, bf16x8& lo) {
  #pragma unroll
  for (int j = 0; j < 4; ++j) {
    hi[j]     = (short)(q0[j] >> 16);
    lo[j]     = (short)(q0[j] & 0xffffu);
    hi[4 + j] = (short)(q1[j] >> 16);
    lo[4 + j] = (short)(q1[j] & 0xffffu);
  }
}

// ---------------- deep-prefetch GEMM ----------------
// At 1 wave/SIMD we own up to 512 VGPRs; hold the ENTIRE per-wave A stream in registers so
// all global loads issue back-to-back (1 LLC latency + stream, instead of ~K/64 serialized
// round trips at the old VGPR budget of 72).
template<int KN> struct APF { u32x4 q[KN >> 4]; };   // KN dwords of packed A per row

template<int KN>
__device__ __forceinline__ void apf_load(APF<KN>& r, const unsigned int* __restrict__ a,
                                         int quad) {
  const unsigned int* ap = a + quad * 8;
  #pragma unroll
  for (int c = 0; c < KN / 64; ++c) {              // all offsets are compile-time immediates
    r.q[4 * c + 0] = *(const u32x4*)(ap + 64 * c + 0);
    r.q[4 * c + 1] = *(const u32x4*)(ap + 64 * c + 4);
    r.q[4 * c + 2] = *(const u32x4*)(ap + 64 * c + 32);
    r.q[4 * c + 3] = *(const u32x4*)(ap + 64 * c + 36);
  }
}

template<int KN>
__device__ __forceinline__ void apf_gemm(const APF<KN>& r, const unsigned short* __restrict__ b,
                                         int quad, f32x4v& cH0, f32x4v& cL0,
                                         f32x4v& cH1, f32x4v& cL1) {
  const unsigned short* bp = b + quad * 8;
  #pragma unroll
  for (int c = 0; c < KN / 64; ++c) {
    bf16x8 a0h, a0l, a1h, a1l;
    unpack16(r.q[4 * c + 0], r.q[4 * c + 1], a0h, a0l);
    unpack16(r.q[4 * c + 2], r.q[4 * c + 3], a1h, a1l);
    bf16x8 b0 = *(const bf16x8*)(bp + 64 * c);
    bf16x8 b1 = *(const bf16x8*)(bp + 64 * c + 32);
    cH0 = __builtin_amdgcn_mfma_f32_16x16x32_bf16(a0h, b0, cH0, 0, 0, 0);
    cL0 = __builtin_amdgcn_mfma_f32_16x16x32_bf16(a0l, b0, cL0, 0, 0, 0);
    cH1 = __builtin_amdgcn_mfma_f32_16x16x32_bf16(a1h, b1, cH1, 0, 0, 0);
    cL1 = __builtin_amdgcn_mfma_f32_16x16x32_bf16(a1l, b1, cL1, 0, 0, 0);
  }
}

// Group barrier. Release: __syncthreads drains vmem (vmcnt(0)) -> atomic stores are at LLC
// before the relaxed counter add. Acquire: after the poll succeeds, ONE acquire atomic load
// makes the compiler emit buffer_inv (L1+L2 invalidate, dirty lines kept) so the post-barrier
// PLAIN loads fetch fresh data from LLC. One cache-op per WG per phase.
__device__ __forceinline__ void gbarrier(unsigned int* myc, int tid, unsigned int tgt) {
  __syncthreads();
  if (tid == 0) {
    __hip_atomic_fetch_add(myc, 1u, __ATOMIC_RELAXED, __HIP_MEMORY_SCOPE_AGENT);
    while (__hip_atomic_load(myc, __ATOMIC_RELAXED, __HIP_MEMORY_SCOPE_AGENT) < tgt)
      __builtin_amdgcn_s_sleep(1);
    (void)__hip_atomic_load(myc, __ATOMIC_ACQUIRE, __HIP_MEMORY_SCOPE_AGENT);
  }
  __syncthreads();
}

// ---------------- persistent GRU ----------------
// 256 WGs x 256 thr, 1 WG/CU. WG (l, rb, cb) owns rows [32rb,32rb+32), h/z/r cols
// [16cb,16cb+16) of layer l. 4 independent rb-groups of 64 WGs; 2 group barriers/super-step.
__global__ void __launch_bounds__(256, 1) gru_kernel(
    const float* __restrict__ Wzr0, const float* __restrict__ bzr0,
    const float* __restrict__ Wh0,  const float* __restrict__ bh0,
    const float* __restrict__ Wzr1, const float* __restrict__ bzr1,
    const float* __restrict__ Wh1,  const float* __restrict__ bh1,
    const unsigned int* __restrict__ x_pk, unsigned int* __restrict__ hp,
    unsigned int* __restrict__ zs, unsigned int* __restrict__ cnt,
    float* __restrict__ out)
{
  extern __shared__ __align__(16) unsigned char smem[];
  const int bid = blockIdx.x, tid = threadIdx.x;
  const int w = tid >> 6, lane = tid & 63, quad = lane >> 4, l16 = lane & 15;
  const int l  = bid >> 7;          // layer
  const int rb = (bid >> 5) & 3;    // row block (sync group)
  const int cb = bid & 31;          // column block
  const int r0 = rb << 5;
  const int c0 = cb << 4;
  const int K  = l ? 1024 : 768;
  const int KI = l ? 512 : 256;     // input-part K (x for L0, h0 for L1)
  const int ldw = K + 8;            // +8 shorts padding

  unsigned short* wlds = (unsigned short*)smem;                 // [48 cols][ldw]: z(16) r(16) h(16)
  float* s_lds = (float*)(smem + ((48 * ldw * 2 + 15) & ~15));  // [32][16] fp32 master state
  float* r_lds = s_lds + 512;                                   // [32][16] r gate
  float* pscr  = r_lds + 512;                                   // [2][16][16] phase-B partials

  const float* Wzr = l ? Wzr1 : Wzr0;
  const float* Wh  = l ? Wh1 : Wh0;
  for (int idx = tid; idx < 16 * K; idx += 256) {
    int j = idx / K, k = idx - j * K;
    wlds[j * ldw + k]        = f2bf(Wzr[k * (2 * DD) + c0 + j]);        // z cols
    wlds[(16 + j) * ldw + k] = f2bf(Wzr[k * (2 * DD) + DD + c0 + j]);   // r cols
    wlds[(32 + j) * ldw + k] = f2bf(Wh[k * DD + c0 + j]);               // h cols
  }
  for (int idx = tid; idx < 512; idx += 256) s_lds[idx] = 0.f;
  const float bz = (l ? bzr1 : bzr0)[c0 + l16];
  const float br = (l ? bzr1 : bzr0)[DD + c0 + l16];
  const float bh = (l ? bh1 : bh0)[c0 + l16];
  __syncthreads();

  unsigned int* myc = cnt + rb * 32;   // per-group counter, own cache line
  unsigned int rnd = 0;

  for (int s = 0; s <= NT; ++s) {
    const int p  = (s + 1) & 1;        // read parity
    const int pw = s & 1;              // write parity
    const bool act = l ? (s >= 1) : (s < NT);
    const int t = l ? (s - 1) : s;

    // ============ phase A: zr = sigmoid([in | h] Wzr + b); stage z*s, keep r local ============
    if (act) {
      const int rowHalf = w >> 1, isR = w & 1;   // waves 0,2: z; 1,3: r
      const int gRow = r0 + (rowHalf << 4) + l16;
      f32x4v cH0 = {0,0,0,0}, cL0 = {0,0,0,0}, cH1 = {0,0,0,0}, cL1 = {0,0,0,0};
      const unsigned short* bseg = wlds + (isR * 16 + l16) * ldw;
      if (l == 0) {
        APF<256> A1; APF<512> A2;
        apf_load(A1, x_pk + ((long)gRow * NT + t) * DIN, quad);
        apf_load(A2, hp + ((p * 2 + 0) * NB + gRow) * DD, quad);
        __builtin_amdgcn_sched_barrier(0);      // pin: all loads issued before compute
        apf_gemm(A1, bseg, quad, cH0, cL0, cH1, cL1);
        apf_gemm(A2, bseg + 256, quad, cH0, cL0, cH1, cL1);
      } else {
        APF<512> A1; APF<512> A2;
        apf_load(A1, hp + ((p * 2 + 0) * NB + gRow) * DD, quad);
        apf_load(A2, hp + ((p * 2 + 1) * NB + gRow) * DD, quad);
        __builtin_amdgcn_sched_barrier(0);
        apf_gemm(A1, bseg, quad, cH0, cL0, cH1, cL1);
        apf_gemm(A2, bseg + 512, quad, cH0, cL0, cH1, cL1);
      }
      #pragma unroll
      for (int i = 0; i < 4; ++i) {
        float pre = (cH0[i] + cL0[i]) + (cH1[i] + cL1[i]) + (isR ? br : bz);
        float g = 1.f / (1.f + __expf(-pre));
        int rloc = (rowHalf << 4) + (quad << 2) + i;
        if (!isR) {
          float sv = s_lds[rloc * 16 + l16];
          __hip_atomic_store(&zs[((long)l * NB + r0 + rloc) * DD + c0 + l16],
                             packf(g * sv), __ATOMIC_RELAXED, __HIP_MEMORY_SCOPE_AGENT);
        } else {
          r_lds[rloc * 16 + l16] = g;
        }
      }
    }

    // Pre-barrier prefetch of phase-B input-K stream (waves 0,1). x_pk is constant; h0[p]
    // was published by the end-of-step-(s-1) barrier -> loads issued here (after that
    // barrier's acquire) are coherent. They complete while we poll, so after the barrier
    // only the zs stream (waves 2,3) pays LLC latency.
    const int srcB = w >> 1, rowHalfB = w & 1;   // waves 0,1: input-K; 2,3: zs-K
    const int gRowB = r0 + (rowHalfB << 4) + l16;
    APF<256> PBx; APF<512> PBh;
    if (act && srcB == 0) {
      if (l == 0) apf_load(PBx, x_pk + ((long)gRowB * NT + t) * DIN, quad);
      else        apf_load(PBh, hp + ((p * 2 + 0) * NB + gRowB) * DD, quad);
      __builtin_amdgcn_sched_barrier(0);
    }
    ++rnd;
    gbarrier(myc, tid, 64u * rnd);

    // ============ phase B: h = r*s + (1-r)*tanh([in | z*s] Wh + b) ============
    if (act) {
      f32x4v cH0 = {0,0,0,0}, cL0 = {0,0,0,0}, cH1 = {0,0,0,0}, cL1 = {0,0,0,0};
      const unsigned short* hseg = wlds + (32 + l16) * ldw;
      if (srcB == 0) {
        if (l == 0) apf_gemm(PBx, hseg, quad, cH0, cL0, cH1, cL1);
        else        apf_gemm(PBh, hseg, quad, cH0, cL0, cH1, cL1);
      } else {
        APF<512> Z;
        apf_load(Z, zs + ((long)l * NB + gRowB) * DD, quad);
        __builtin_amdgcn_sched_barrier(0);
        apf_gemm(Z, hseg + KI, quad, cH0, cL0, cH1, cL1);
      }
      f32x4v tot;
      #pragma unroll
      for (int i = 0; i < 4; ++i) tot[i] = (cH0[i] + cL0[i]) + (cH1[i] + cL1[i]);
      if (srcB == 1) {
        #pragma unroll
        for (int i = 0; i < 4; ++i)
          pscr[rowHalfB * 256 + ((quad << 2) + i) * 16 + l16] = tot[i];
      }
      __syncthreads();   // act is WG-uniform -> legal
      if (srcB == 0) {
        #pragma unroll
        for (int i = 0; i < 4; ++i) {
          int rloc = (rowHalfB << 4) + (quad << 2) + i;
          float pre = tot[i] + pscr[rowHalfB * 256 + ((quad << 2) + i) * 16 + l16] + bh;
          float ax = fabsf(pre), e = __expf(-2.f * ax);
          float th = (1.f - e) / (1.f + e);
          th = (pre < 0.f) ? -th : th;
          float rv = r_lds[rloc * 16 + l16];
          float sv = s_lds[rloc * 16 + l16];
          float h = rv * sv + (1.f - rv) * th;
          s_lds[rloc * 16 + l16] = h;
          __hip_atomic_store(&hp[((pw * 2 + l) * NB + r0 + rloc) * DD + c0 + l16],
                             packf(h), __ATOMIC_RELAXED, __HIP_MEMORY_SCOPE_AGENT);
          if (l) out[((long)(r0 + rloc) * NT + t) * DD + c0 + l16] = h;
        }
      }
    }
    ++rnd;
    gbarrier(myc, tid, 64u * rnd);
  }
}

// ---------------- host ----------------
extern "C" void kernel_launch(void* const* d_in, const int* in_sizes, int n_in,
                              void* d_out, int out_size, void* d_ws, size_t ws_size,
                              hipStream_t stream) {
  const float* x    = (const float*)d_in[0];
  const float* Wzr0 = (const float*)d_in[1];
  const float* bzr0 = (const float*)d_in[2];
  const float* Wh0  = (const float*)d_in[3];
  const float* bh0  = (const float*)d_in[4];
  const float* Wzr1 = (const float*)d_in[5];
  const float* bzr1 = (const float*)d_in[6];
  const float* bh1_ = (const float*)d_in[8];
  const float* Wh1  = (const float*)d_in[7];
  float* out = (float*)d_out;

  char* pp = (char*)d_ws;
  unsigned int* cnt  = (unsigned int*)pp;  pp += 1024;
  unsigned int* x_pk = (unsigned int*)pp;  pp += (size_t)NB * NT * DIN * 4;  // packed hi|lo
  unsigned int* hp   = (unsigned int*)pp;  pp += (size_t)2 * 2 * NB * DD * 4;
  unsigned int* zs   = (unsigned int*)pp;  pp += (size_t)2 * NB * DD * 4;

  hipLaunchKernelGGL(prep_kernel, dim3(1024), dim3(256), 0, stream, x, x_pk, hp, cnt);

  const int SMEM = ((48 * (1024 + 8) * 2 + 15) & ~15) + 3 * 512 * 4;  // 105216 B
  (void)hipFuncSetAttribute((const void*)gru_kernel,
                            hipFuncAttributeMaxDynamicSharedMemorySize, SMEM);
  // 256 WGs x 256 thr, >80 KB LDS each -> exactly 1 WG/CU, all co-resident (no deadlock)
  hipLaunchKernelGGL(gru_kernel, dim3(256), dim3(256), SMEM, stream,
                     Wzr0, bzr0, Wh0, bh0, Wzr1, bzr1, Wh1, bh1_,
                     x_pk, hp, zs, cnt, out);
}